// Round 17
// baseline (562.391 us; speedup 1.0000x reference)
//
#include <hip/hip_runtime.h>
#include <math.h>

#define NN    8192
#define FIN   512
#define HF    256
#define ME    65536

typedef _Float16 f16x8 __attribute__((ext_vector_type(8)));
typedef __fp16 pk16x2 __attribute__((ext_vector_type(2)));   // cvt_pkrtz result type
typedef float f32x4  __attribute__((ext_vector_type(4)));

// exact fp16 hi/lo split (RTZ pack; remainder exact; residual O(2^-20))
__device__ inline void split_pk(float a0, float a1, unsigned& hi, unsigned& lo) {
    pk16x2 h = __builtin_amdgcn_cvt_pkrtz(a0, a1);
    float r0 = a0 - (float)h[0];
    float r1 = a1 - (float)h[1];
    pk16x2 l = __builtin_amdgcn_cvt_pkrtz(r0, r1);
    hi = __builtin_bit_cast(unsigned, h);
    lo = __builtin_bit_cast(unsigned, l);
}
// round-to-nearest f16 pack of 2 floats (unbiased quantization)
__device__ inline unsigned pack_f16rn(float a0, float a1) {
    _Float16 h0 = (_Float16)a0, h1 = (_Float16)a1;
    unsigned u0 = (unsigned)__builtin_bit_cast(unsigned short, h0);
    unsigned u1 = (unsigned)__builtin_bit_cast(unsigned short, h1);
    return u0 | (u1 << 16);
}
__device__ inline unsigned short f16rn(float v) {
    return __builtin_bit_cast(unsigned short, (_Float16)v);
}
__device__ inline void split_f16(float v, short& hi, short& lo) {
    _Float16 h = (_Float16)v;
    _Float16 l = (_Float16)(v - (float)h);
    hi = __builtin_bit_cast(short, h);
    lo = __builtin_bit_cast(short, l);
}
__device__ inline float eluf(float v) { return v > 0.f ? v : expm1f(v); }

// async global(16B per lane) -> LDS (wave-uniform base + lane*16)
__device__ inline void gload16(const void* g, void* l) {
    __builtin_amdgcn_global_load_lds(
        (const __attribute__((address_space(1))) unsigned int*)g,
        (__attribute__((address_space(3))) unsigned int*)l, 16, 0, 0);
}

// ------- column sums of adj (+1 self loop) -> deg; optional adj->f16 RN copy --
// grid (8,128): 64 rows/block, 1024 blocks -> 4 blocks/CU.
// Row loop unrolled x2 with independent accumulators (breaks add chain, 2x MLP).
__global__ __launch_bounds__(256) void colsum_cv(const float* __restrict__ adj,
                                                 float* __restrict__ deg,
                                                 unsigned short* __restrict__ adjh) {
    int c = (blockIdx.x * 256 + threadIdx.x) * 4;
    int r0 = blockIdx.y * 64;
    float4 s0 = make_float4(0.f, 0.f, 0.f, 0.f);
    float4 s1 = make_float4(0.f, 0.f, 0.f, 0.f);
    for (int r = r0; r < r0 + 64; r += 2) {
        float4 v0 = *(const float4*)(adj + (size_t)r * NN + c);
        float4 v1 = *(const float4*)(adj + (size_t)(r + 1) * NN + c);
        s0.x += v0.x; s0.y += v0.y; s0.z += v0.z; s0.w += v0.w;
        s1.x += v1.x; s1.y += v1.y; s1.z += v1.z; s1.w += v1.w;
        if (adjh) {
            ushort4 h0, h1;
            h0.x = f16rn(v0.x); h0.y = f16rn(v0.y); h0.z = f16rn(v0.z); h0.w = f16rn(v0.w);
            h1.x = f16rn(v1.x); h1.y = f16rn(v1.y); h1.z = f16rn(v1.z); h1.w = f16rn(v1.w);
            *(ushort4*)(adjh + (size_t)r * NN + c) = h0;
            *(ushort4*)(adjh + (size_t)(r + 1) * NN + c) = h1;
        }
    }
    float4 s = make_float4(s0.x + s1.x, s0.y + s1.y, s0.z + s1.z, s0.w + s1.w);
    if (blockIdx.y == 0) { s.x += 1.f; s.y += 1.f; s.z += 1.f; s.w += 1.f; }
    atomicAdd(&deg[c + 0], s.x);
    atomicAdd(&deg[c + 1], s.y);
    atomicAdd(&deg[c + 2], s.z);
    atomicAdd(&deg[c + 3], s.w);
}

// ---------------- W [K][N] fp32 -> split f16 Wt_hi/lo [N][K] ----------------
__global__ __launch_bounds__(256) void trans_w_split(const float* __restrict__ src,
                                                     short* __restrict__ dsth,
                                                     short* __restrict__ dstl,
                                                     int K, int lgN) {
    int idx = blockIdx.x * 256 + threadIdx.x;
    int N = 1 << lgN;
    int k = idx >> lgN, n = idx & (N - 1);
    short h, l;
    split_f16(src[idx], h, l);
    dsth[(size_t)n * K + k] = h;
    dstl[(size_t)n * K + k] = l;
}

// -------- split-f16 MFMA GEMM: C = A(fp32) @ Bt^T. BM=64, BN=128, BK=64. -----
// PASSES=2: A->RN-f16 single (GCN1; /deg damping absorbs quant error).
// PASSES=3: A hi+lo, drops only al*bl ~2^-22 => fp32-grade (GCN2/head).
// WBT=1: additionally emit transposed split f16 output (feeds adj_prop).
template <int PASSES, int WBT>
__global__ __launch_bounds__(256, 2) void mfma_gemm(
    const float* __restrict__ A, const short* __restrict__ BtH,
    const short* __restrict__ BtL, float* __restrict__ C,
    short* __restrict__ CtH, short* __restrict__ CtL, int M, int K, int N)
{
    __shared__ __align__(16) char smem[49152];
    char* sAh = smem;                          // 64*64 f16 (8KB)
    char* sAl = smem + 8192;                   // 64*64 f16 (8KB, PASSES=3 only)
    char* sBh = smem + 16384;                  // 128*64 f16 (16KB)
    char* sBl = smem + 32768;                  // 128*64 f16 (16KB)
    float* sT = (float*)smem;                  // 64*136 fp32 overlay (epilogue)
    const int tid = threadIdx.x, lane = tid & 63, wid = tid >> 6;
    const int wm = wid >> 1, wn = wid & 1;
    const int m0 = blockIdx.x * 64, n0 = blockIdx.y * 128;
    const int lhi = lane >> 4, llo = lane & 15;

    f32x4 acc[2][4];
    #pragma unroll
    for (int mi = 0; mi < 2; ++mi)
        #pragma unroll
        for (int ni = 0; ni < 4; ++ni) acc[mi][ni] = (f32x4){0.f, 0.f, 0.f, 0.f};

    for (int kt = 0; kt < K; kt += 64) {
        float4 av[4];
        #pragma unroll
        for (int it = 0; it < 4; ++it) {
            int h = tid + 256 * it;
            int r = h >> 4, hs = h & 15, slot = hs >> 1, half = hs & 1;
            int gk = ((slot ^ (r & 7)) * 2 + half) * 4;
            av[it] = *(const float4*)(A + (size_t)(m0 + r) * K + kt + gk);
        }
        __syncthreads();
        #pragma unroll
        for (int it = 0; it < 4; ++it) {
            int u = tid + 256 * it;
            int c = u >> 3, s = u & 7;
            size_t off = (size_t)(n0 + c) * K + kt + (s ^ (c & 7)) * 8;
            gload16(BtH + off, sBh + u * 16);
            gload16(BtL + off, sBl + u * 16);
        }
        #pragma unroll
        for (int it = 0; it < 4; ++it) {
            int h = tid + 256 * it;
            if (PASSES == 3) {
                uint2 wh, wl;
                split_pk(av[it].x, av[it].y, wh.x, wl.x);
                split_pk(av[it].z, av[it].w, wh.y, wl.y);
                *(uint2*)(sAh + h * 8) = wh;
                *(uint2*)(sAl + h * 8) = wl;
            } else {
                uint2 wh;
                wh.x = pack_f16rn(av[it].x, av[it].y);
                wh.y = pack_f16rn(av[it].z, av[it].w);
                *(uint2*)(sAh + h * 8) = wh;
            }
        }
        __syncthreads();
        #pragma unroll
        for (int ks = 0; ks < 2; ++ks) {
            f16x8 afh[2], afl[2], bfh[4], bfl[4];
            #pragma unroll
            for (int mi = 0; mi < 2; ++mi) {
                int R = wm * 32 + mi * 16 + llo;
                int boff = R * 128 + (((ks * 4 + lhi) ^ (R & 7)) << 4);
                afh[mi] = *(const f16x8*)(sAh + boff);
                if (PASSES == 3) afl[mi] = *(const f16x8*)(sAl + boff);
            }
            #pragma unroll
            for (int ni = 0; ni < 4; ++ni) {
                int Cc = wn * 64 + ni * 16 + llo;
                int boff = Cc * 128 + (((ks * 4 + lhi) ^ (Cc & 7)) << 4);
                bfh[ni] = *(const f16x8*)(sBh + boff);
                bfl[ni] = *(const f16x8*)(sBl + boff);
            }
            #pragma unroll
            for (int mi = 0; mi < 2; ++mi)
                #pragma unroll
                for (int ni = 0; ni < 4; ++ni) {
                    acc[mi][ni] = __builtin_amdgcn_mfma_f32_16x16x32_f16(afh[mi], bfh[ni], acc[mi][ni], 0, 0, 0);
                    acc[mi][ni] = __builtin_amdgcn_mfma_f32_16x16x32_f16(afh[mi], bfl[ni], acc[mi][ni], 0, 0, 0);
                    if (PASSES == 3)
                        acc[mi][ni] = __builtin_amdgcn_mfma_f32_16x16x32_f16(afl[mi], bfh[ni], acc[mi][ni], 0, 0, 0);
                }
        }
    }

    if (WBT) {
        __syncthreads();   // LDS reads done; overlay sT
        #pragma unroll
        for (int mi = 0; mi < 2; ++mi)
            #pragma unroll
            for (int ni = 0; ni < 4; ++ni) {
                int lr = wm * 32 + mi * 16 + lhi * 4;
                int lc = wn * 64 + ni * 16 + llo;
                int R0 = m0 + lr;
                int Cc = n0 + lc;
                #pragma unroll
                for (int r = 0; r < 4; ++r) {
                    C[(size_t)(R0 + r) * N + Cc] = acc[mi][ni][r];
                    sT[(lr + r) * 136 + lc] = acc[mi][ni][r];
                }
            }
        __syncthreads();
        int c = tid >> 1, ih = (tid & 1) * 32;
        unsigned bh[16], bl[16];
        #pragma unroll
        for (int j = 0; j < 32; j += 2)
            split_pk(sT[(ih + j) * 136 + c], sT[(ih + j + 1) * 136 + c],
                     bh[j >> 1], bl[j >> 1]);
        int4* dh = (int4*)(CtH + (size_t)(n0 + c) * M + m0 + ih);
        int4* dl = (int4*)(CtL + (size_t)(n0 + c) * M + m0 + ih);
        #pragma unroll
        for (int q = 0; q < 4; ++q) { dh[q] = ((int4*)bh)[q]; dl[q] = ((int4*)bl)[q]; }
    } else {
        #pragma unroll
        for (int mi = 0; mi < 2; ++mi)
            #pragma unroll
            for (int ni = 0; ni < 4; ++ni) {
                int R0 = m0 + wm * 32 + mi * 16 + lhi * 4;
                int Cc = n0 + wn * 64 + ni * 16 + llo;
                #pragma unroll
                for (int r = 0; r < 4; ++r)
                    C[(size_t)(R0 + r) * N + Cc] = acc[mi][ni][r];
            }
    }
}

// ---- adj propagate partial from pre-quantized f16 adj (PURE gload_lds) -------
// part[ky] = adjh[:, kchunk_ky] @ Y[kchunk_ky, :]; KSPLIT=2, BM=64 BN=64 BK=64.
// Double-buffered LDS (2x24KB), T3 2-phase schedule: issue DMA(t+1) BEFORE
// MFMA(t), one barrier per tile -> DMA latency hides under the MFMA cluster.
// 48KB LDS -> 3 blocks/CU.
__global__ __launch_bounds__(256, 3) void adj_prop_g(const unsigned short* __restrict__ adjh,
                                                     const short* __restrict__ YtH,
                                                     const short* __restrict__ YtL,
                                                     float* part0, float* part1)
{
    // buffer b at smem + b*24576: sA +0 (8K), sBh +8192 (8K), sBl +16384 (8K)
    __shared__ __align__(16) char smem[49152];
    const int tid = threadIdx.x, lane = tid & 63, wid = tid >> 6;
    const int wm = wid >> 1, wn = wid & 1;
    const int bid = blockIdx.x;
    const int g  = bid & 7;                    // XCD (round-robin dispatch)
    const int ky = g >> 2;                     // K-chunk: XCD 0-3 -> 0, 4-7 -> 1
    const int gx = g & 3;
    const int s  = bid >> 3;                   // 0..127
    const int bm = gx * 32 + (s >> 2), bn = s & 3;
    const int i0 = bm * 64, c0 = bn * 64;
    const int kbase = ky * (NN / 2);
    const int lhi = lane >> 4, llo = lane & 15;

    f32x4 acc[2][2];
    #pragma unroll
    for (int mi = 0; mi < 2; ++mi)
        #pragma unroll
        for (int ni = 0; ni < 2; ++ni) acc[mi][ni] = (f32x4){0.f, 0.f, 0.f, 0.f};

#define ISSUE_DMA(T, B)                                                         \
    {                                                                           \
        const int KT = kbase + (T) * 64;                                        \
        char* base = smem + (B) * 24576;                                        \
        _Pragma("unroll")                                                       \
        for (int it = 0; it < 2; ++it) {                                        \
            int u = tid + 256 * it;                                             \
            int r = u >> 3, sq = u & 7;                                         \
            gload16(adjh + (size_t)(i0 + r) * NN + KT + ((sq ^ (r & 7)) * 8),   \
                    base + u * 16);                                             \
        }                                                                       \
        _Pragma("unroll")                                                       \
        for (int it = 0; it < 2; ++it) {                                        \
            int u = tid + 256 * it;                                             \
            int c = u >> 3, sq = u & 7;                                         \
            size_t off = (size_t)(c0 + c) * NN + KT + (sq ^ (c & 7)) * 8;       \
            gload16(YtH + off, base + 8192 + u * 16);                           \
            gload16(YtL + off, base + 16384 + u * 16);                          \
        }                                                                       \
    }

    ISSUE_DMA(0, 0);
    __syncthreads();                           // tile 0 DMA drained
    for (int t = 0; t < 64; ++t) {
        const int cur = t & 1;
        if (t + 1 < 64) ISSUE_DMA(t + 1, cur ^ 1);   // flies under MFMA
        {
            const char* ah = smem + cur * 24576;
            const char* bh = ah + 8192;
            const char* bl = ah + 16384;
            #pragma unroll
            for (int ks = 0; ks < 2; ++ks) {
                f16x8 af[2], bfh[2], bfl[2];
                #pragma unroll
                for (int mi = 0; mi < 2; ++mi) {
                    int R = wm * 32 + mi * 16 + llo;
                    int boff = R * 128 + (((ks * 4 + lhi) ^ (R & 7)) << 4);
                    af[mi] = *(const f16x8*)(ah + boff);
                }
                #pragma unroll
                for (int ni = 0; ni < 2; ++ni) {
                    int Cc = wn * 32 + ni * 16 + llo;
                    int boff = Cc * 128 + (((ks * 4 + lhi) ^ (Cc & 7)) << 4);
                    bfh[ni] = *(const f16x8*)(bh + boff);
                    bfl[ni] = *(const f16x8*)(bl + boff);
                }
                #pragma unroll
                for (int mi = 0; mi < 2; ++mi)
                    #pragma unroll
                    for (int ni = 0; ni < 2; ++ni) {
                        acc[mi][ni] = __builtin_amdgcn_mfma_f32_16x16x32_f16(af[mi], bfh[ni], acc[mi][ni], 0, 0, 0);
                        acc[mi][ni] = __builtin_amdgcn_mfma_f32_16x16x32_f16(af[mi], bfl[ni], acc[mi][ni], 0, 0, 0);
                    }
            }
        }
        __syncthreads();                       // drains DMA(t+1); joins waves
    }
#undef ISSUE_DMA

    // epilogue: sT transpose -> coalesced float4 partial writes
    float* sT = (float*)smem;                  // 64 x 68 fp32 (17.4 KB, in buf0)
    #pragma unroll
    for (int mi = 0; mi < 2; ++mi)
        #pragma unroll
        for (int ni = 0; ni < 2; ++ni) {
            int lr = wm * 32 + mi * 16 + lhi * 4;
            int lc = wn * 32 + ni * 16 + llo;
            #pragma unroll
            for (int r = 0; r < 4; ++r)
                sT[(lr + r) * 68 + lc] = acc[mi][ni][r];
        }
    __syncthreads();
    float* po = ky == 0 ? part0 : part1;
    int row = tid >> 2, quad = tid & 3;
    float4* prow = (float4*)(po + (size_t)(i0 + row) * HF + c0 + quad * 16);
    #pragma unroll
    for (int q = 0; q < 4; ++q)
        prow[q] = *(const float4*)&sT[row * 68 + quad * 16 + q * 4];
}

// ---- FALLBACK (small ws): adj_prop with per-tile fp32->f16 convert -----------
__global__ __launch_bounds__(256, 4) void adj_prop_cv(const float* __restrict__ adj,
                                                      const short* __restrict__ YtH,
                                                      const short* __restrict__ YtL,
                                                      float* part0, float* part1)
{
    __shared__ __align__(16) char smem[24576];
    const int tid = threadIdx.x, lane = tid & 63, wid = tid >> 6;
    const int wm = wid >> 1, wn = wid & 1;
    const int bid = blockIdx.x;
    const int g  = bid & 7;
    const int ky = g >> 2;
    const int gx = g & 3;
    const int s  = bid >> 3;
    const int bm = gx * 32 + (s >> 2), bn = s & 3;
    const int i0 = bm * 64, c0 = bn * 64;
    const int kbase = ky * (NN / 2);
    const int lhi = lane >> 4, llo = lane & 15;

    f32x4 acc[2][2];
    #pragma unroll
    for (int mi = 0; mi < 2; ++mi)
        #pragma unroll
        for (int ni = 0; ni < 2; ++ni) acc[mi][ni] = (f32x4){0.f, 0.f, 0.f, 0.f};

    float4 avA[4], avB[4];

#define LOAD_ADJ(KT, AV)                                                        \
    {                                                                           \
        _Pragma("unroll")                                                       \
        for (int it = 0; it < 4; ++it) {                                        \
            int h = tid + 256 * it;                                             \
            int r = h >> 4, hs = h & 15, slot = hs >> 1, half = hs & 1;         \
            int gk = ((slot ^ (r & 7)) * 2 + half) * 4;                         \
            AV[it] = *(const float4*)(adj + (size_t)(i0 + r) * NN + (KT) + gk); \
        }                                                                       \
    }
#define GLOAD_B(KT)                                                             \
    {                                                                           \
        _Pragma("unroll")                                                       \
        for (int it = 0; it < 2; ++it) {                                        \
            int u = tid + 256 * it;                                             \
            int c = u >> 3, s2 = u & 7;                                         \
            size_t off = (size_t)(c0 + c) * NN + (KT) + (s2 ^ (c & 7)) * 8;     \
            gload16(YtH + off, smem + 8192 + u * 16);                           \
            gload16(YtL + off, smem + 16384 + u * 16);                          \
        }                                                                       \
    }
#define CONVERT_A(AV)                                                           \
    {                                                                           \
        _Pragma("unroll")                                                       \
        for (int it = 0; it < 4; ++it) {                                        \
            int h = tid + 256 * it;                                             \
            uint2 wh;                                                           \
            wh.x = pack_f16rn(AV[it].x, AV[it].y);                              \
            wh.y = pack_f16rn(AV[it].z, AV[it].w);                              \
            *(uint2*)(smem + h * 8) = wh;                                       \
        }                                                                       \
    }
#define DO_MFMA()                                                               \
    {                                                                           \
        const char* ah = smem;                                                  \
        const char* bh = smem + 8192;                                           \
        const char* bl = smem + 16384;                                          \
        _Pragma("unroll")                                                       \
        for (int ks = 0; ks < 2; ++ks) {                                        \
            f16x8 af[2], bfh[2], bfl[2];                                        \
            _Pragma("unroll")                                                   \
            for (int mi = 0; mi < 2; ++mi) {                                    \
                int R = wm * 32 + mi * 16 + llo;                                \
                int boff = R * 128 + (((ks * 4 + lhi) ^ (R & 7)) << 4);         \
                af[mi] = *(const f16x8*)(ah + boff);                            \
            }                                                                   \
            _Pragma("unroll")                                                   \
            for (int ni = 0; ni < 2; ++ni) {                                    \
                int Cc = wn * 32 + ni * 16 + llo;                               \
                int boff = Cc * 128 + (((ks * 4 + lhi) ^ (Cc & 7)) << 4);       \
                bfh[ni] = *(const f16x8*)(bh + boff);                           \
                bfl[ni] = *(const f16x8*)(bl + boff);                           \
            }                                                                   \
            _Pragma("unroll")                                                   \
            for (int mi = 0; mi < 2; ++mi)                                      \
                _Pragma("unroll")                                               \
                for (int ni = 0; ni < 2; ++ni) {                                \
                    acc[mi][ni] = __builtin_amdgcn_mfma_f32_16x16x32_f16(af[mi], bfh[ni], acc[mi][ni], 0, 0, 0); \
                    acc[mi][ni] = __builtin_amdgcn_mfma_f32_16x16x32_f16(af[mi], bfl[ni], acc[mi][ni], 0, 0, 0); \
                }                                                               \
        }                                                                       \
    }

    LOAD_ADJ(kbase, avA);
    LOAD_ADJ(kbase + 64, avB);
    for (int t = 0; t < 64; t += 2) {
        __syncthreads();
        GLOAD_B(kbase + t * 64);
        CONVERT_A(avA);
        __syncthreads();
        if (t + 2 < 64) LOAD_ADJ(kbase + (t + 2) * 64, avA);
        DO_MFMA();
        __syncthreads();
        GLOAD_B(kbase + (t + 1) * 64);
        CONVERT_A(avB);
        __syncthreads();
        if (t + 3 < 64) LOAD_ADJ(kbase + (t + 3) * 64, avB);
        DO_MFMA();
    }
#undef LOAD_ADJ
#undef GLOAD_B
#undef CONVERT_A
#undef DO_MFMA

    __syncthreads();
    float* sT = (float*)smem;
    #pragma unroll
    for (int mi = 0; mi < 2; ++mi)
        #pragma unroll
        for (int ni = 0; ni < 2; ++ni) {
            int lr = wm * 32 + mi * 16 + lhi * 4;
            int lc = wn * 32 + ni * 16 + llo;
            #pragma unroll
            for (int r = 0; r < 4; ++r)
                sT[(lr + r) * 68 + lc] = acc[mi][ni][r];
        }
    __syncthreads();
    float* po = ky == 0 ? part0 : part1;
    int row = tid >> 2, quad = tid & 3;
    float4* prow = (float4*)(po + (size_t)(i0 + row) * HF + c0 + quad * 16);
    #pragma unroll
    for (int q = 0; q < 4; ++q)
        prow[q] = *(const float4*)&sT[row * 68 + quad * 16 + q * 4];
}

// ---------------- H = elu((part0 + part1 + Y)/deg). H may alias part0. -------
__global__ __launch_bounds__(256) void adj_reduce(const float* part0,
                                                  const float* part1,
                                                  const float* __restrict__ Y,
                                                  const float* __restrict__ deg,
                                                  float* H) {
    int idx = blockIdx.x * 256 + threadIdx.x;
    int i = idx >> 6;
    float4 p0 = ((const float4*)part0)[idx];
    float4 p1 = ((const float4*)part1)[idx];
    float4 y  = ((const float4*)Y)[idx];
    float dinv = 1.f / deg[i];
    float4 v;
    v.x = eluf((p0.x + p1.x + y.x) * dinv);
    v.y = eluf((p0.y + p1.y + y.y) * dinv);
    v.z = eluf((p0.z + p1.z + y.z) * dinv);
    v.w = eluf((p0.w + p1.w + y.w) * dinv);
    ((float4*)H)[idx] = v;
}

// ---------------- wa2 = W @ a2 ----------------
__global__ __launch_bounds__(512) void wa2_kernel(const float* __restrict__ W,
                                                  const float* __restrict__ a2,
                                                  float* __restrict__ wa2) {
    int i = threadIdx.x;
    float s = 0.f;
    for (int j = 0; j < HF; ++j) s += W[(size_t)i * HF + j] * a2[j];
    wa2[i] = s;
}

// ---------------- s2 = x @ wa2 ----------------
__global__ __launch_bounds__(256) void s2_kernel(const float* __restrict__ x,
                                                 const float* __restrict__ wa2,
                                                 float* __restrict__ s2) {
    int lane = threadIdx.x & 63, wv = threadIdx.x >> 6;
    int row = blockIdx.x * 4 + wv;
    const float4* xr = (const float4*)(x + (size_t)row * FIN);
    const float4* w4 = (const float4*)wa2;
    float s = 0.f;
    #pragma unroll
    for (int t = 0; t < 2; ++t) {
        float4 a = xr[lane + 64 * t], b = w4[lane + 64 * t];
        s += a.x * b.x + a.y * b.y + a.z * b.z + a.w * b.w;
    }
    #pragma unroll
    for (int off = 32; off > 0; off >>= 1) s += __shfl_down(s, off);
    if (lane == 0) s2[row] = s;
}

// ---------------- top-16 of s2 ----------------
__global__ __launch_bounds__(256) void top16_kernel(const float* __restrict__ s2,
                                                    int* __restrict__ Tflag) {
    __shared__ float sv[NN];
    __shared__ float rv[256];
    __shared__ int   ri[256];
    int tid = threadIdx.x;
    for (int i = tid; i < NN; i += 256) sv[i] = s2[i];
    __syncthreads();
    for (int it = 0; it < 16; ++it) {
        float best = -INFINITY; int bi = NN;
        for (int i = tid; i < NN; i += 256) {
            float v = sv[i];
            if (v > best) { best = v; bi = i; }
        }
        rv[tid] = best; ri[tid] = bi;
        __syncthreads();
        for (int off = 128; off > 0; off >>= 1) {
            if (tid < off) {
                float v2 = rv[tid + off]; int i2 = ri[tid + off];
                if (v2 > rv[tid] || (v2 == rv[tid] && i2 < ri[tid])) {
                    rv[tid] = v2; ri[tid] = i2;
                }
            }
            __syncthreads();
        }
        if (tid == 0) { int wi = ri[0]; Tflag[wi] = 1; sv[wi] = -INFINITY; }
        __syncthreads();
    }
}

// ---------------- column sums of Y: total[k] and sum over T rows ----------------
__global__ __launch_bounds__(256) void colsum_T(const float* __restrict__ Y,
                                                const int* __restrict__ Tflag,
                                                float* __restrict__ total,
                                                float* __restrict__ sumT) {
    int k = threadIdx.x;
    int r0 = blockIdx.x * 128;
    float t = 0.f, tt = 0.f;
    for (int r = r0; r < r0 + 128; ++r) {
        float v = Y[(size_t)r * HF + k];
        t += v;
        if (Tflag[r]) tt += v;
    }
    atomicAdd(&total[k], t);
    atomicAdd(&sumT[k], tt);
}

// ---------------- GCN2 propagate+elu, in place ----------------
__global__ __launch_bounds__(256) void gcn2_combine(float* __restrict__ Y,
                                                    const int* __restrict__ Tflag,
                                                    const float* __restrict__ sumT,
                                                    const float* __restrict__ total) {
    int idx = blockIdx.x * 256 + threadIdx.x;
    int i = idx >> 8, k = idx & 255;
    float v;
    if (Tflag[i]) v = total[k] / 8192.0f;
    else          v = (sumT[k] + Y[idx]) / 17.0f;
    Y[idx] = v > 0.f ? v : expm1f(v);
}

// ---------------- bilinear head + per-edge loss term ----------------
__global__ __launch_bounds__(256) void bilinear_kernel(
    const float* __restrict__ XB, const float* __restrict__ H,
    const float* __restrict__ Hs, const int* __restrict__ src,
    const int* __restrict__ dst, const float* __restrict__ labels,
    const float* __restrict__ bil_b,
    float* __restrict__ out_logits, float* __restrict__ out_pred,
    float* __restrict__ partials)
{
    __shared__ float wterm[4];
    int lane = threadIdx.x & 63;
    int wv = threadIdx.x >> 6;
    int e = blockIdx.x * 4 + wv;
    int s = src[e], d = dst[e];
    const float4* xb = (const float4*)(XB + (size_t)s * 512);
    const float4* h1 = (const float4*)(H + (size_t)d * HF);
    const float4* h2 = (const float4*)(Hs + (size_t)d * HF);
    float4 a = xb[lane], b = h1[lane];
    float sum = a.x * b.x + a.y * b.y + a.z * b.z + a.w * b.w;
    a = xb[64 + lane]; b = h2[lane];
    sum += a.x * b.x + a.y * b.y + a.z * b.z + a.w * b.w;
    #pragma unroll
    for (int off = 32; off > 0; off >>= 1) sum += __shfl_down(sum, off);
    if (lane == 0) {
        float l = sum + bil_b[0];
        out_logits[e] = l;
        out_pred[e] = (l >= 0.f) ? 1.f : 0.f;
        float lab = labels[e];
        wterm[wv] = fmaxf(l, 0.f) - l * lab + log1pf(expf(-fabsf(l)));
    }
    __syncthreads();
    if (threadIdx.x == 0)
        partials[blockIdx.x] = wterm[0] + wterm[1] + wterm[2] + wterm[3];
}

__global__ __launch_bounds__(256) void loss_finalize(const float* __restrict__ partials,
                                                     float* __restrict__ out) {
    __shared__ float s[256];
    int tid = threadIdx.x;
    float t = 0.f;
    for (int i = tid; i < ME / 4; i += 256) t += partials[i];
    s[tid] = t; __syncthreads();
    for (int off = 128; off > 0; off >>= 1) {
        if (tid < off) s[tid] += s[tid + off];
        __syncthreads();
    }
    if (tid == 0) out[0] = s[0] * (1.0f / (float)ME);
}

// ---------------- launch ----------------
extern "C" void kernel_launch(void* const* d_in, const int* in_sizes, int n_in,
                              void* d_out, int out_size, void* d_ws, size_t ws_size,
                              hipStream_t stream) {
    const int*   src    = (const int*)d_in[0];
    const int*   dst    = (const int*)d_in[1];
    const float* labels = (const float*)d_in[2];
    const float* adj    = (const float*)d_in[3];
    const float* x      = (const float*)d_in[4];
    const float* W1_0   = (const float*)d_in[5];
    const float* W1_1   = (const float*)d_in[6];
    const float* W2_0   = (const float*)d_in[7];
    const float* W2_1   = (const float*)d_in[8];
    const float* W      = (const float*)d_in[9];
    const float* a2     = (const float*)d_in[11];   // a1 unused (monotone-invariant)
    const float* bilw   = (const float*)d_in[12];
    const float* bilb   = (const float*)d_in[13];

    float* w = (float*)d_ws;
    float* deg    = w + 0;                  // 8192
    float* s2v    = w + 8192;               // 8192
    float* wa2v   = w + 16384;              // 512
    float* sumT   = w + 16896;              // 256
    float* total  = w + 17152;              // 256
    float* sum2T  = w + 17408;              // 256
    float* tot2   = w + 17664;              // 256
    float* lossp  = w + 17920;              // 16384
    int*   Tflag  = (int*)(w + 34304);      // 8192
    short* W10tH  = (short*)(w + 42496);    // 131072 sh (65536 f)
    short* W10tL  = (short*)(w + 108032);
    short* W11tH  = (short*)(w + 173568);   // 65536 sh (32768 f)
    short* W11tL  = (short*)(w + 206336);
    short* W20tH  = (short*)(w + 239104);   // 131072 sh (65536 f)
    short* W20tL  = (short*)(w + 304640);
    short* W21tH  = (short*)(w + 370176);   // 65536 sh (32768 f)
    short* W21tL  = (short*)(w + 402944);
    short* bilwtH = (short*)(w + 435712);   // 262144 sh (131072 f)
    short* bilwtL = (short*)(w + 566784);
    float* bufY   = w + 697856;             // 2M f
    short* YbtH   = (short*)(w + 2795008);  // 2M sh (1M f)
    short* YbtL   = (short*)(w + 3843584);
    float* bufH1  = w + 4892160;            // 2M f
    float* bufH   = w + 6989312;            // 2M f (also part0)
    float* bufHs  = w + 9086464;            // 2M f (also part1)
    unsigned short* adjh = (unsigned short*)(w + 11183616);  // 64M sh (32M f)
    float* XB     = bufY;                   // overlays bufY+Ybt (4M f, dead by then)
    // high-water with adjh: 44,738,048 floats = 179 MB; without: 44.7 MB
    const bool big = ws_size >= (size_t)44738048 * sizeof(float);

    float* out       = (float*)d_out;
    float* out_logit = out + 1;
    float* out_pred  = out + 1 + ME;

    hipMemsetAsync(deg, 0, NN * sizeof(float), stream);
    hipMemsetAsync(sumT, 0, 1024 * sizeof(float), stream);
    hipMemsetAsync(Tflag, 0, NN * sizeof(int), stream);

    trans_w_split<<<512, 256, 0, stream>>>(W1_0, W10tH, W10tL, 512, 8);
    trans_w_split<<<256, 256, 0, stream>>>(W1_1, W11tH, W11tL, 256, 8);
    trans_w_split<<<512, 256, 0, stream>>>(W2_0, W20tH, W20tL, 512, 8);
    trans_w_split<<<256, 256, 0, stream>>>(W2_1, W21tH, W21tL, 256, 8);
    trans_w_split<<<1024, 256, 0, stream>>>(bilw, bilwtH, bilwtL, 512, 9);

    colsum_cv<<<dim3(8, 128), 256, 0, stream>>>(adj, deg, big ? adjh : nullptr);

    // ---- GCN1 (2-pass split-f16 MFMA; errors damped by /deg ~ 4097) ----
    mfma_gemm<2, 1><<<dim3(128, 2), 256, 0, stream>>>(x, W10tH, W10tL, bufY, YbtH, YbtL, NN, FIN, HF);
    if (big) adj_prop_g<<<1024, 256, 0, stream>>>(adjh, YbtH, YbtL, bufH, bufHs);
    else     adj_prop_cv<<<1024, 256, 0, stream>>>(adj, YbtH, YbtL, bufH, bufHs);
    adj_reduce<<<2048, 256, 0, stream>>>(bufH, bufHs, bufY, deg, bufH1);
    mfma_gemm<2, 1><<<dim3(128, 2), 256, 0, stream>>>(bufH1, W11tH, W11tL, bufY, YbtH, YbtL, NN, HF, HF);
    if (big) adj_prop_g<<<1024, 256, 0, stream>>>(adjh, YbtH, YbtL, bufH, bufHs);
    else     adj_prop_cv<<<1024, 256, 0, stream>>>(adj, YbtH, YbtL, bufH, bufHs);
    adj_reduce<<<2048, 256, 0, stream>>>(bufH, bufHs, bufY, deg, bufH);   // in-place: bufH = H

    // ---- similarity graph (exact fp32 ordering) ----
    wa2_kernel<<<1, 512, 0, stream>>>(W, a2, wa2v);
    s2_kernel<<<NN / 4, 256, 0, stream>>>(x, wa2v, s2v);
    top16_kernel<<<1, 256, 0, stream>>>(s2v, Tflag);

    // ---- GCN2 (3-pass split-f16 MFMA: residual ~2^-22, fp32-grade) ----
    mfma_gemm<3, 0><<<dim3(128, 2), 256, 0, stream>>>(x, W20tH, W20tL, bufY,
                                                      (short*)nullptr, (short*)nullptr, NN, 512, 256);
    colsum_T<<<64, 256, 0, stream>>>(bufY, Tflag, total, sumT);
    gcn2_combine<<<NN, 256, 0, stream>>>(bufY, Tflag, sumT, total);
    mfma_gemm<3, 0><<<dim3(128, 2), 256, 0, stream>>>(bufY, W21tH, W21tL, bufHs,
                                                      (short*)nullptr, (short*)nullptr, NN, 256, 256);
    colsum_T<<<64, 256, 0, stream>>>(bufHs, Tflag, tot2, sum2T);
    gcn2_combine<<<NN, 256, 0, stream>>>(bufHs, Tflag, sum2T, tot2);  // bufHs = H_

    // ---- bilinear head (3-pass split-f16); XB overlays dead bufY/Ybt ----
    mfma_gemm<3, 0><<<dim3(128, 4), 256, 0, stream>>>(x, bilwtH, bilwtL, XB,
                                                      (short*)nullptr, (short*)nullptr, NN, 512, 512);
    bilinear_kernel<<<ME / 4, 256, 0, stream>>>(XB, bufH, bufHs, src, dst, labels, bilb,
                                                out_logit, out_pred, lossp);
    loss_finalize<<<1, 256, 0, stream>>>(lossp, out);
}

// Round 18
// 540.895 us; speedup vs baseline: 1.0397x; 1.0397x over previous
//
#include <hip/hip_runtime.h>
#include <math.h>

#define NN    8192
#define FIN   512
#define HF    256
#define ME    65536

typedef _Float16 f16x8 __attribute__((ext_vector_type(8)));
typedef __fp16 pk16x2 __attribute__((ext_vector_type(2)));   // cvt_pkrtz result type
typedef float f32x4  __attribute__((ext_vector_type(4)));

// exact fp16 hi/lo split (RTZ pack; remainder exact; residual O(2^-20))
__device__ inline void split_pk(float a0, float a1, unsigned& hi, unsigned& lo) {
    pk16x2 h = __builtin_amdgcn_cvt_pkrtz(a0, a1);
    float r0 = a0 - (float)h[0];
    float r1 = a1 - (float)h[1];
    pk16x2 l = __builtin_amdgcn_cvt_pkrtz(r0, r1);
    hi = __builtin_bit_cast(unsigned, h);
    lo = __builtin_bit_cast(unsigned, l);
}
// round-to-nearest f16 pack of 2 floats (unbiased quantization)
__device__ inline unsigned pack_f16rn(float a0, float a1) {
    _Float16 h0 = (_Float16)a0, h1 = (_Float16)a1;
    unsigned u0 = (unsigned)__builtin_bit_cast(unsigned short, h0);
    unsigned u1 = (unsigned)__builtin_bit_cast(unsigned short, h1);
    return u0 | (u1 << 16);
}
__device__ inline unsigned short f16rn(float v) {
    return __builtin_bit_cast(unsigned short, (_Float16)v);
}
__device__ inline void split_f16(float v, short& hi, short& lo) {
    _Float16 h = (_Float16)v;
    _Float16 l = (_Float16)(v - (float)h);
    hi = __builtin_bit_cast(short, h);
    lo = __builtin_bit_cast(short, l);
}
__device__ inline float eluf(float v) { return v > 0.f ? v : expm1f(v); }

// async global(16B per lane) -> LDS (wave-uniform base + lane*16)
__device__ inline void gload16(const void* g, void* l) {
    __builtin_amdgcn_global_load_lds(
        (const __attribute__((address_space(1))) unsigned int*)g,
        (__attribute__((address_space(3))) unsigned int*)l, 16, 0, 0);
}

// ------- column sums of adj (+1 self loop) -> deg; optional adj->f16 RN copy --
// grid (8,128): 64 rows/block, 1024 blocks -> 4 blocks/CU (best measured, R14).
__global__ __launch_bounds__(256) void colsum_cv(const float* __restrict__ adj,
                                                 float* __restrict__ deg,
                                                 unsigned short* __restrict__ adjh) {
    int c = (blockIdx.x * 256 + threadIdx.x) * 4;
    int r0 = blockIdx.y * 64;
    float4 s = make_float4(0.f, 0.f, 0.f, 0.f);
    for (int r = r0; r < r0 + 64; ++r) {
        float4 v = *(const float4*)(adj + (size_t)r * NN + c);
        s.x += v.x; s.y += v.y; s.z += v.z; s.w += v.w;
        if (adjh) {
            ushort4 h;
            h.x = f16rn(v.x); h.y = f16rn(v.y); h.z = f16rn(v.z); h.w = f16rn(v.w);
            *(ushort4*)(adjh + (size_t)r * NN + c) = h;
        }
    }
    if (blockIdx.y == 0) { s.x += 1.f; s.y += 1.f; s.z += 1.f; s.w += 1.f; }
    atomicAdd(&deg[c + 0], s.x);
    atomicAdd(&deg[c + 1], s.y);
    atomicAdd(&deg[c + 2], s.z);
    atomicAdd(&deg[c + 3], s.w);
}

// ---------------- W [K][N] fp32 -> split f16 Wt_hi/lo [N][K] ----------------
__global__ __launch_bounds__(256) void trans_w_split(const float* __restrict__ src,
                                                     short* __restrict__ dsth,
                                                     short* __restrict__ dstl,
                                                     int K, int lgN) {
    int idx = blockIdx.x * 256 + threadIdx.x;
    int N = 1 << lgN;
    int k = idx >> lgN, n = idx & (N - 1);
    short h, l;
    split_f16(src[idx], h, l);
    dsth[(size_t)n * K + k] = h;
    dstl[(size_t)n * K + k] = l;
}

// -------- split-f16 MFMA GEMM: C = A(fp32) @ Bt^T. BM=64, BN=128, BK=64. -----
// PASSES=2: A->RN-f16 single (GCN1; /deg damping absorbs quant error).
// PASSES=3: A hi+lo, drops only al*bl ~2^-22 => fp32-grade (GCN2/head).
// WBT=1: additionally emit transposed split f16 output (feeds adj_prop).
template <int PASSES, int WBT>
__global__ __launch_bounds__(256, 2) void mfma_gemm(
    const float* __restrict__ A, const short* __restrict__ BtH,
    const short* __restrict__ BtL, float* __restrict__ C,
    short* __restrict__ CtH, short* __restrict__ CtL, int M, int K, int N)
{
    __shared__ __align__(16) char smem[49152];
    char* sAh = smem;                          // 64*64 f16 (8KB)
    char* sAl = smem + 8192;                   // 64*64 f16 (8KB, PASSES=3 only)
    char* sBh = smem + 16384;                  // 128*64 f16 (16KB)
    char* sBl = smem + 32768;                  // 128*64 f16 (16KB)
    float* sT = (float*)smem;                  // 64*136 fp32 overlay (epilogue)
    const int tid = threadIdx.x, lane = tid & 63, wid = tid >> 6;
    const int wm = wid >> 1, wn = wid & 1;
    const int m0 = blockIdx.x * 64, n0 = blockIdx.y * 128;
    const int lhi = lane >> 4, llo = lane & 15;

    f32x4 acc[2][4];
    #pragma unroll
    for (int mi = 0; mi < 2; ++mi)
        #pragma unroll
        for (int ni = 0; ni < 4; ++ni) acc[mi][ni] = (f32x4){0.f, 0.f, 0.f, 0.f};

    for (int kt = 0; kt < K; kt += 64) {
        float4 av[4];
        #pragma unroll
        for (int it = 0; it < 4; ++it) {
            int h = tid + 256 * it;
            int r = h >> 4, hs = h & 15, slot = hs >> 1, half = hs & 1;
            int gk = ((slot ^ (r & 7)) * 2 + half) * 4;
            av[it] = *(const float4*)(A + (size_t)(m0 + r) * K + kt + gk);
        }
        __syncthreads();
        #pragma unroll
        for (int it = 0; it < 4; ++it) {
            int u = tid + 256 * it;
            int c = u >> 3, s = u & 7;
            size_t off = (size_t)(n0 + c) * K + kt + (s ^ (c & 7)) * 8;
            gload16(BtH + off, sBh + u * 16);
            gload16(BtL + off, sBl + u * 16);
        }
        #pragma unroll
        for (int it = 0; it < 4; ++it) {
            int h = tid + 256 * it;
            if (PASSES == 3) {
                uint2 wh, wl;
                split_pk(av[it].x, av[it].y, wh.x, wl.x);
                split_pk(av[it].z, av[it].w, wh.y, wl.y);
                *(uint2*)(sAh + h * 8) = wh;
                *(uint2*)(sAl + h * 8) = wl;
            } else {
                uint2 wh;
                wh.x = pack_f16rn(av[it].x, av[it].y);
                wh.y = pack_f16rn(av[it].z, av[it].w);
                *(uint2*)(sAh + h * 8) = wh;
            }
        }
        __syncthreads();
        #pragma unroll
        for (int ks = 0; ks < 2; ++ks) {
            f16x8 afh[2], afl[2], bfh[4], bfl[4];
            #pragma unroll
            for (int mi = 0; mi < 2; ++mi) {
                int R = wm * 32 + mi * 16 + llo;
                int boff = R * 128 + (((ks * 4 + lhi) ^ (R & 7)) << 4);
                afh[mi] = *(const f16x8*)(sAh + boff);
                if (PASSES == 3) afl[mi] = *(const f16x8*)(sAl + boff);
            }
            #pragma unroll
            for (int ni = 0; ni < 4; ++ni) {
                int Cc = wn * 64 + ni * 16 + llo;
                int boff = Cc * 128 + (((ks * 4 + lhi) ^ (Cc & 7)) << 4);
                bfh[ni] = *(const f16x8*)(sBh + boff);
                bfl[ni] = *(const f16x8*)(sBl + boff);
            }
            #pragma unroll
            for (int mi = 0; mi < 2; ++mi)
                #pragma unroll
                for (int ni = 0; ni < 4; ++ni) {
                    acc[mi][ni] = __builtin_amdgcn_mfma_f32_16x16x32_f16(afh[mi], bfh[ni], acc[mi][ni], 0, 0, 0);
                    acc[mi][ni] = __builtin_amdgcn_mfma_f32_16x16x32_f16(afh[mi], bfl[ni], acc[mi][ni], 0, 0, 0);
                    if (PASSES == 3)
                        acc[mi][ni] = __builtin_amdgcn_mfma_f32_16x16x32_f16(afl[mi], bfh[ni], acc[mi][ni], 0, 0, 0);
                }
        }
    }

    if (WBT) {
        __syncthreads();   // LDS reads done; overlay sT
        #pragma unroll
        for (int mi = 0; mi < 2; ++mi)
            #pragma unroll
            for (int ni = 0; ni < 4; ++ni) {
                int lr = wm * 32 + mi * 16 + lhi * 4;
                int lc = wn * 64 + ni * 16 + llo;
                int R0 = m0 + lr;
                int Cc = n0 + lc;
                #pragma unroll
                for (int r = 0; r < 4; ++r) {
                    C[(size_t)(R0 + r) * N + Cc] = acc[mi][ni][r];
                    sT[(lr + r) * 136 + lc] = acc[mi][ni][r];
                }
            }
        __syncthreads();
        int c = tid >> 1, ih = (tid & 1) * 32;
        unsigned bh[16], bl[16];
        #pragma unroll
        for (int j = 0; j < 32; j += 2)
            split_pk(sT[(ih + j) * 136 + c], sT[(ih + j + 1) * 136 + c],
                     bh[j >> 1], bl[j >> 1]);
        int4* dh = (int4*)(CtH + (size_t)(n0 + c) * M + m0 + ih);
        int4* dl = (int4*)(CtL + (size_t)(n0 + c) * M + m0 + ih);
        #pragma unroll
        for (int q = 0; q < 4; ++q) { dh[q] = ((int4*)bh)[q]; dl[q] = ((int4*)bl)[q]; }
    } else {
        #pragma unroll
        for (int mi = 0; mi < 2; ++mi)
            #pragma unroll
            for (int ni = 0; ni < 4; ++ni) {
                int R0 = m0 + wm * 32 + mi * 16 + lhi * 4;
                int Cc = n0 + wn * 64 + ni * 16 + llo;
                #pragma unroll
                for (int r = 0; r < 4; ++r)
                    C[(size_t)(R0 + r) * N + Cc] = acc[mi][ni][r];
            }
    }
}

// ---- adj propagate partial from pre-quantized f16 adj (PURE gload_lds) -------
// part[ky] = adjh[:, kchunk_ky] @ Y[kchunk_ky, :]; KSPLIT=2, BM=64 BN=64 BK=64,
// 256 threads, grid 1024 -> 4 blocks/CU (24KB LDS). Zero staging regs/convert.
__global__ __launch_bounds__(256, 4) void adj_prop_g(const unsigned short* __restrict__ adjh,
                                                     const short* __restrict__ YtH,
                                                     const short* __restrict__ YtL,
                                                     float* part0, float* part1)
{
    // sA +0 (8K), sBh +8192 (8K), sBl +16384 (8K)
    __shared__ __align__(16) char smem[24576];
    const int tid = threadIdx.x, lane = tid & 63, wid = tid >> 6;
    const int wm = wid >> 1, wn = wid & 1;
    const int bid = blockIdx.x;
    const int g  = bid & 7;                    // XCD (round-robin dispatch)
    const int ky = g >> 2;                     // K-chunk: XCD 0-3 -> 0, 4-7 -> 1
    const int gx = g & 3;
    const int s  = bid >> 3;                   // 0..127
    const int bm = gx * 32 + (s >> 2), bn = s & 3;
    const int i0 = bm * 64, c0 = bn * 64;
    const int kbase = ky * (NN / 2);
    const int lhi = lane >> 4, llo = lane & 15;

    f32x4 acc[2][2];
    #pragma unroll
    for (int mi = 0; mi < 2; ++mi)
        #pragma unroll
        for (int ni = 0; ni < 2; ++ni) acc[mi][ni] = (f32x4){0.f, 0.f, 0.f, 0.f};

    for (int t = 0; t < 64; ++t) {
        const int KT = kbase + t * 64;
        __syncthreads();                       // previous tile's MFMA LDS reads done
        #pragma unroll
        for (int it = 0; it < 2; ++it) {
            int u = tid + 256 * it;
            int r = u >> 3, sq = u & 7;
            gload16(adjh + (size_t)(i0 + r) * NN + KT + ((sq ^ (r & 7)) * 8),
                    smem + u * 16);
        }
        #pragma unroll
        for (int it = 0; it < 2; ++it) {
            int u = tid + 256 * it;
            int c = u >> 3, sq = u & 7;
            size_t off = (size_t)(c0 + c) * NN + KT + (sq ^ (c & 7)) * 8;
            gload16(YtH + off, smem + 8192 + u * 16);
            gload16(YtL + off, smem + 16384 + u * 16);
        }
        __syncthreads();                       // DMA drained, LDS ready
        {
            const char* ah = smem;
            const char* bh = smem + 8192;
            const char* bl = smem + 16384;
            #pragma unroll
            for (int ks = 0; ks < 2; ++ks) {
                f16x8 af[2], bfh[2], bfl[2];
                #pragma unroll
                for (int mi = 0; mi < 2; ++mi) {
                    int R = wm * 32 + mi * 16 + llo;
                    int boff = R * 128 + (((ks * 4 + lhi) ^ (R & 7)) << 4);
                    af[mi] = *(const f16x8*)(ah + boff);
                }
                #pragma unroll
                for (int ni = 0; ni < 2; ++ni) {
                    int Cc = wn * 32 + ni * 16 + llo;
                    int boff = Cc * 128 + (((ks * 4 + lhi) ^ (Cc & 7)) << 4);
                    bfh[ni] = *(const f16x8*)(bh + boff);
                    bfl[ni] = *(const f16x8*)(bl + boff);
                }
                #pragma unroll
                for (int mi = 0; mi < 2; ++mi)
                    #pragma unroll
                    for (int ni = 0; ni < 2; ++ni) {
                        acc[mi][ni] = __builtin_amdgcn_mfma_f32_16x16x32_f16(af[mi], bfh[ni], acc[mi][ni], 0, 0, 0);
                        acc[mi][ni] = __builtin_amdgcn_mfma_f32_16x16x32_f16(af[mi], bfl[ni], acc[mi][ni], 0, 0, 0);
                    }
            }
        }
    }

    // epilogue: sT transpose -> coalesced float4 partial writes
    __syncthreads();
    float* sT = (float*)smem;                  // 64 x 68 fp32 (17.4 KB, fits 24K)
    #pragma unroll
    for (int mi = 0; mi < 2; ++mi)
        #pragma unroll
        for (int ni = 0; ni < 2; ++ni) {
            int lr = wm * 32 + mi * 16 + lhi * 4;
            int lc = wn * 32 + ni * 16 + llo;
            #pragma unroll
            for (int r = 0; r < 4; ++r)
                sT[(lr + r) * 68 + lc] = acc[mi][ni][r];
        }
    __syncthreads();
    float* po = ky == 0 ? part0 : part1;
    int row = tid >> 2, quad = tid & 3;
    float4* prow = (float4*)(po + (size_t)(i0 + row) * HF + c0 + quad * 16);
    #pragma unroll
    for (int q = 0; q < 4; ++q)
        prow[q] = *(const float4*)&sT[row * 68 + quad * 16 + q * 4];
}

// ---- FALLBACK (small ws): adj_prop with per-tile fp32->f16 convert -----------
__global__ __launch_bounds__(256, 4) void adj_prop_cv(const float* __restrict__ adj,
                                                      const short* __restrict__ YtH,
                                                      const short* __restrict__ YtL,
                                                      float* part0, float* part1)
{
    __shared__ __align__(16) char smem[24576];
    const int tid = threadIdx.x, lane = tid & 63, wid = tid >> 6;
    const int wm = wid >> 1, wn = wid & 1;
    const int bid = blockIdx.x;
    const int g  = bid & 7;
    const int ky = g >> 2;
    const int gx = g & 3;
    const int s  = bid >> 3;
    const int bm = gx * 32 + (s >> 2), bn = s & 3;
    const int i0 = bm * 64, c0 = bn * 64;
    const int kbase = ky * (NN / 2);
    const int lhi = lane >> 4, llo = lane & 15;

    f32x4 acc[2][2];
    #pragma unroll
    for (int mi = 0; mi < 2; ++mi)
        #pragma unroll
        for (int ni = 0; ni < 2; ++ni) acc[mi][ni] = (f32x4){0.f, 0.f, 0.f, 0.f};

    float4 avA[4], avB[4];

#define LOAD_ADJ(KT, AV)                                                        \
    {                                                                           \
        _Pragma("unroll")                                                       \
        for (int it = 0; it < 4; ++it) {                                        \
            int h = tid + 256 * it;                                             \
            int r = h >> 4, hs = h & 15, slot = hs >> 1, half = hs & 1;         \
            int gk = ((slot ^ (r & 7)) * 2 + half) * 4;                         \
            AV[it] = *(const float4*)(adj + (size_t)(i0 + r) * NN + (KT) + gk); \
        }                                                                       \
    }
#define GLOAD_B(KT)                                                             \
    {                                                                           \
        _Pragma("unroll")                                                       \
        for (int it = 0; it < 2; ++it) {                                        \
            int u = tid + 256 * it;                                             \
            int c = u >> 3, s2 = u & 7;                                         \
            size_t off = (size_t)(c0 + c) * NN + (KT) + (s2 ^ (c & 7)) * 8;     \
            gload16(YtH + off, smem + 8192 + u * 16);                           \
            gload16(YtL + off, smem + 16384 + u * 16);                          \
        }                                                                       \
    }
#define CONVERT_A(AV)                                                           \
    {                                                                           \
        _Pragma("unroll")                                                       \
        for (int it = 0; it < 4; ++it) {                                        \
            int h = tid + 256 * it;                                             \
            uint2 wh;                                                           \
            wh.x = pack_f16rn(AV[it].x, AV[it].y);                              \
            wh.y = pack_f16rn(AV[it].z, AV[it].w);                              \
            *(uint2*)(smem + h * 8) = wh;                                       \
        }                                                                       \
    }
#define DO_MFMA()                                                               \
    {                                                                           \
        const char* ah = smem;                                                  \
        const char* bh = smem + 8192;                                           \
        const char* bl = smem + 16384;                                          \
        _Pragma("unroll")                                                       \
        for (int ks = 0; ks < 2; ++ks) {                                        \
            f16x8 af[2], bfh[2], bfl[2];                                        \
            _Pragma("unroll")                                                   \
            for (int mi = 0; mi < 2; ++mi) {                                    \
                int R = wm * 32 + mi * 16 + llo;                                \
                int boff = R * 128 + (((ks * 4 + lhi) ^ (R & 7)) << 4);         \
                af[mi] = *(const f16x8*)(ah + boff);                            \
            }                                                                   \
            _Pragma("unroll")                                                   \
            for (int ni = 0; ni < 2; ++ni) {                                    \
                int Cc = wn * 32 + ni * 16 + llo;                               \
                int boff = Cc * 128 + (((ks * 4 + lhi) ^ (Cc & 7)) << 4);       \
                bfh[ni] = *(const f16x8*)(bh + boff);                           \
                bfl[ni] = *(const f16x8*)(bl + boff);                           \
            }                                                                   \
            _Pragma("unroll")                                                   \
            for (int mi = 0; mi < 2; ++mi)                                      \
                _Pragma("unroll")                                               \
                for (int ni = 0; ni < 2; ++ni) {                                \
                    acc[mi][ni] = __builtin_amdgcn_mfma_f32_16x16x32_f16(af[mi], bfh[ni], acc[mi][ni], 0, 0, 0); \
                    acc[mi][ni] = __builtin_amdgcn_mfma_f32_16x16x32_f16(af[mi], bfl[ni], acc[mi][ni], 0, 0, 0); \
                }                                                               \
        }                                                                       \
    }

    LOAD_ADJ(kbase, avA);
    LOAD_ADJ(kbase + 64, avB);
    for (int t = 0; t < 64; t += 2) {
        __syncthreads();
        GLOAD_B(kbase + t * 64);
        CONVERT_A(avA);
        __syncthreads();
        if (t + 2 < 64) LOAD_ADJ(kbase + (t + 2) * 64, avA);
        DO_MFMA();
        __syncthreads();
        GLOAD_B(kbase + (t + 1) * 64);
        CONVERT_A(avB);
        __syncthreads();
        if (t + 3 < 64) LOAD_ADJ(kbase + (t + 3) * 64, avB);
        DO_MFMA();
    }
#undef LOAD_ADJ
#undef GLOAD_B
#undef CONVERT_A
#undef DO_MFMA

    __syncthreads();
    float* sT = (float*)smem;
    #pragma unroll
    for (int mi = 0; mi < 2; ++mi)
        #pragma unroll
        for (int ni = 0; ni < 2; ++ni) {
            int lr = wm * 32 + mi * 16 + lhi * 4;
            int lc = wn * 32 + ni * 16 + llo;
            #pragma unroll
            for (int r = 0; r < 4; ++r)
                sT[(lr + r) * 68 + lc] = acc[mi][ni][r];
        }
    __syncthreads();
    float* po = ky == 0 ? part0 : part1;
    int row = tid >> 2, quad = tid & 3;
    float4* prow = (float4*)(po + (size_t)(i0 + row) * HF + c0 + quad * 16);
    #pragma unroll
    for (int q = 0; q < 4; ++q)
        prow[q] = *(const float4*)&sT[row * 68 + quad * 16 + q * 4];
}

// ---------------- H = elu((part0 + part1 + Y)/deg). H may alias part0. -------
__global__ __launch_bounds__(256) void adj_reduce(const float* part0,
                                                  const float* part1,
                                                  const float* __restrict__ Y,
                                                  const float* __restrict__ deg,
                                                  float* H) {
    int idx = blockIdx.x * 256 + threadIdx.x;
    int i = idx >> 6;
    float4 p0 = ((const float4*)part0)[idx];
    float4 p1 = ((const float4*)part1)[idx];
    float4 y  = ((const float4*)Y)[idx];
    float dinv = 1.f / deg[i];
    float4 v;
    v.x = eluf((p0.x + p1.x + y.x) * dinv);
    v.y = eluf((p0.y + p1.y + y.y) * dinv);
    v.z = eluf((p0.z + p1.z + y.z) * dinv);
    v.w = eluf((p0.w + p1.w + y.w) * dinv);
    ((float4*)H)[idx] = v;
}

// ---------------- wa2 = W @ a2 ----------------
__global__ __launch_bounds__(512) void wa2_kernel(const float* __restrict__ W,
                                                  const float* __restrict__ a2,
                                                  float* __restrict__ wa2) {
    int i = threadIdx.x;
    float s = 0.f;
    for (int j = 0; j < HF; ++j) s += W[(size_t)i * HF + j] * a2[j];
    wa2[i] = s;
}

// ---------------- s2 = x @ wa2 ----------------
__global__ __launch_bounds__(256) void s2_kernel(const float* __restrict__ x,
                                                 const float* __restrict__ wa2,
                                                 float* __restrict__ s2) {
    int lane = threadIdx.x & 63, wv = threadIdx.x >> 6;
    int row = blockIdx.x * 4 + wv;
    const float4* xr = (const float4*)(x + (size_t)row * FIN);
    const float4* w4 = (const float4*)wa2;
    float s = 0.f;
    #pragma unroll
    for (int t = 0; t < 2; ++t) {
        float4 a = xr[lane + 64 * t], b = w4[lane + 64 * t];
        s += a.x * b.x + a.y * b.y + a.z * b.z + a.w * b.w;
    }
    #pragma unroll
    for (int off = 32; off > 0; off >>= 1) s += __shfl_down(s, off);
    if (lane == 0) s2[row] = s;
}

// ---------------- top-16 of s2 ----------------
__global__ __launch_bounds__(256) void top16_kernel(const float* __restrict__ s2,
                                                    int* __restrict__ Tflag) {
    __shared__ float sv[NN];
    __shared__ float rv[256];
    __shared__ int   ri[256];
    int tid = threadIdx.x;
    for (int i = tid; i < NN; i += 256) sv[i] = s2[i];
    __syncthreads();
    for (int it = 0; it < 16; ++it) {
        float best = -INFINITY; int bi = NN;
        for (int i = tid; i < NN; i += 256) {
            float v = sv[i];
            if (v > best) { best = v; bi = i; }
        }
        rv[tid] = best; ri[tid] = bi;
        __syncthreads();
        for (int off = 128; off > 0; off >>= 1) {
            if (tid < off) {
                float v2 = rv[tid + off]; int i2 = ri[tid + off];
                if (v2 > rv[tid] || (v2 == rv[tid] && i2 < ri[tid])) {
                    rv[tid] = v2; ri[tid] = i2;
                }
            }
            __syncthreads();
        }
        if (tid == 0) { int wi = ri[0]; Tflag[wi] = 1; sv[wi] = -INFINITY; }
        __syncthreads();
    }
}

// ---------------- column sums of Y: total[k] and sum over T rows ----------------
__global__ __launch_bounds__(256) void colsum_T(const float* __restrict__ Y,
                                                const int* __restrict__ Tflag,
                                                float* __restrict__ total,
                                                float* __restrict__ sumT) {
    int k = threadIdx.x;
    int r0 = blockIdx.x * 128;
    float t = 0.f, tt = 0.f;
    for (int r = r0; r < r0 + 128; ++r) {
        float v = Y[(size_t)r * HF + k];
        t += v;
        if (Tflag[r]) tt += v;
    }
    atomicAdd(&total[k], t);
    atomicAdd(&sumT[k], tt);
}

// ---------------- GCN2 propagate+elu, in place ----------------
__global__ __launch_bounds__(256) void gcn2_combine(float* __restrict__ Y,
                                                    const int* __restrict__ Tflag,
                                                    const float* __restrict__ sumT,
                                                    const float* __restrict__ total) {
    int idx = blockIdx.x * 256 + threadIdx.x;
    int i = idx >> 8, k = idx & 255;
    float v;
    if (Tflag[i]) v = total[k] / 8192.0f;
    else          v = (sumT[k] + Y[idx]) / 17.0f;
    Y[idx] = v > 0.f ? v : expm1f(v);
}

// ---------------- bilinear head + per-edge loss term ----------------
__global__ __launch_bounds__(256) void bilinear_kernel(
    const float* __restrict__ XB, const float* __restrict__ H,
    const float* __restrict__ Hs, const int* __restrict__ src,
    const int* __restrict__ dst, const float* __restrict__ labels,
    const float* __restrict__ bil_b,
    float* __restrict__ out_logits, float* __restrict__ out_pred,
    float* __restrict__ partials)
{
    __shared__ float wterm[4];
    int lane = threadIdx.x & 63;
    int wv = threadIdx.x >> 6;
    int e = blockIdx.x * 4 + wv;
    int s = src[e], d = dst[e];
    const float4* xb = (const float4*)(XB + (size_t)s * 512);
    const float4* h1 = (const float4*)(H + (size_t)d * HF);
    const float4* h2 = (const float4*)(Hs + (size_t)d * HF);
    float4 a = xb[lane], b = h1[lane];
    float sum = a.x * b.x + a.y * b.y + a.z * b.z + a.w * b.w;
    a = xb[64 + lane]; b = h2[lane];
    sum += a.x * b.x + a.y * b.y + a.z * b.z + a.w * b.w;
    #pragma unroll
    for (int off = 32; off > 0; off >>= 1) sum += __shfl_down(sum, off);
    if (lane == 0) {
        float l = sum + bil_b[0];
        out_logits[e] = l;
        out_pred[e] = (l >= 0.f) ? 1.f : 0.f;
        float lab = labels[e];
        wterm[wv] = fmaxf(l, 0.f) - l * lab + log1pf(expf(-fabsf(l)));
    }
    __syncthreads();
    if (threadIdx.x == 0)
        partials[blockIdx.x] = wterm[0] + wterm[1] + wterm[2] + wterm[3];
}

__global__ __launch_bounds__(256) void loss_finalize(const float* __restrict__ partials,
                                                     float* __restrict__ out) {
    __shared__ float s[256];
    int tid = threadIdx.x;
    float t = 0.f;
    for (int i = tid; i < ME / 4; i += 256) t += partials[i];
    s[tid] = t; __syncthreads();
    for (int off = 128; off > 0; off >>= 1) {
        if (tid < off) s[tid] += s[tid + off];
        __syncthreads();
    }
    if (tid == 0) out[0] = s[0] * (1.0f / (float)ME);
}

// ---------------- launch ----------------
extern "C" void kernel_launch(void* const* d_in, const int* in_sizes, int n_in,
                              void* d_out, int out_size, void* d_ws, size_t ws_size,
                              hipStream_t stream) {
    const int*   src    = (const int*)d_in[0];
    const int*   dst    = (const int*)d_in[1];
    const float* labels = (const float*)d_in[2];
    const float* adj    = (const float*)d_in[3];
    const float* x      = (const float*)d_in[4];
    const float* W1_0   = (const float*)d_in[5];
    const float* W1_1   = (const float*)d_in[6];
    const float* W2_0   = (const float*)d_in[7];
    const float* W2_1   = (const float*)d_in[8];
    const float* W      = (const float*)d_in[9];
    const float* a2     = (const float*)d_in[11];   // a1 unused (monotone-invariant)
    const float* bilw   = (const float*)d_in[12];
    const float* bilb   = (const float*)d_in[13];

    float* w = (float*)d_ws;
    float* deg    = w + 0;                  // 8192
    float* s2v    = w + 8192;               // 8192
    float* wa2v   = w + 16384;              // 512
    float* sumT   = w + 16896;              // 256
    float* total  = w + 17152;              // 256
    float* sum2T  = w + 17408;              // 256
    float* tot2   = w + 17664;              // 256
    float* lossp  = w + 17920;              // 16384
    int*   Tflag  = (int*)(w + 34304);      // 8192
    short* W10tH  = (short*)(w + 42496);    // 131072 sh (65536 f)
    short* W10tL  = (short*)(w + 108032);
    short* W11tH  = (short*)(w + 173568);   // 65536 sh (32768 f)
    short* W11tL  = (short*)(w + 206336);
    short* W20tH  = (short*)(w + 239104);   // 131072 sh (65536 f)
    short* W20tL  = (short*)(w + 304640);
    short* W21tH  = (short*)(w + 370176);   // 65536 sh (32768 f)
    short* W21tL  = (short*)(w + 402944);
    short* bilwtH = (short*)(w + 435712);   // 262144 sh (131072 f)
    short* bilwtL = (short*)(w + 566784);
    float* bufY   = w + 697856;             // 2M f
    short* YbtH   = (short*)(w + 2795008);  // 2M sh (1M f)
    short* YbtL   = (short*)(w + 3843584);
    float* bufH1  = w + 4892160;            // 2M f
    float* bufH   = w + 6989312;            // 2M f (also part0)
    float* bufHs  = w + 9086464;            // 2M f (also part1)
    unsigned short* adjh = (unsigned short*)(w + 11183616);  // 64M sh (32M f)
    float* XB     = bufY;                   // overlays bufY+Ybt (4M f, dead by then)
    // high-water with adjh: 44,738,048 floats = 179 MB; without: 44.7 MB
    const bool big = ws_size >= (size_t)44738048 * sizeof(float);

    float* out       = (float*)d_out;
    float* out_logit = out + 1;
    float* out_pred  = out + 1 + ME;

    hipMemsetAsync(deg, 0, NN * sizeof(float), stream);
    hipMemsetAsync(sumT, 0, 1024 * sizeof(float), stream);
    hipMemsetAsync(Tflag, 0, NN * sizeof(int), stream);

    trans_w_split<<<512, 256, 0, stream>>>(W1_0, W10tH, W10tL, 512, 8);
    trans_w_split<<<256, 256, 0, stream>>>(W1_1, W11tH, W11tL, 256, 8);
    trans_w_split<<<512, 256, 0, stream>>>(W2_0, W20tH, W20tL, 512, 8);
    trans_w_split<<<256, 256, 0, stream>>>(W2_1, W21tH, W21tL, 256, 8);
    trans_w_split<<<1024, 256, 0, stream>>>(bilw, bilwtH, bilwtL, 512, 9);

    colsum_cv<<<dim3(8, 128), 256, 0, stream>>>(adj, deg, big ? adjh : nullptr);

    // ---- GCN1 (2-pass split-f16 MFMA; errors damped by /deg ~ 4097) ----
    mfma_gemm<2, 1><<<dim3(128, 2), 256, 0, stream>>>(x, W10tH, W10tL, bufY, YbtH, YbtL, NN, FIN, HF);
    if (big) adj_prop_g<<<1024, 256, 0, stream>>>(adjh, YbtH, YbtL, bufH, bufHs);
    else     adj_prop_cv<<<1024, 256, 0, stream>>>(adj, YbtH, YbtL, bufH, bufHs);
    adj_reduce<<<2048, 256, 0, stream>>>(bufH, bufHs, bufY, deg, bufH1);
    mfma_gemm<2, 1><<<dim3(128, 2), 256, 0, stream>>>(bufH1, W11tH, W11tL, bufY, YbtH, YbtL, NN, HF, HF);
    if (big) adj_prop_g<<<1024, 256, 0, stream>>>(adjh, YbtH, YbtL, bufH, bufHs);
    else     adj_prop_cv<<<1024, 256, 0, stream>>>(adj, YbtH, YbtL, bufH, bufHs);
    adj_reduce<<<2048, 256, 0, stream>>>(bufH, bufHs, bufY, deg, bufH);   // in-place: bufH = H

    // ---- similarity graph (exact fp32 ordering) ----
    wa2_kernel<<<1, 512, 0, stream>>>(W, a2, wa2v);
    s2_kernel<<<NN / 4, 256, 0, stream>>>(x, wa2v, s2v);
    top16_kernel<<<1, 256, 0, stream>>>(s2v, Tflag);

    // ---- GCN2 (3-pass split-f16 MFMA: residual ~2^-22, fp32-grade) ----
    mfma_gemm<3, 0><<<dim3(128, 2), 256, 0, stream>>>(x, W20tH, W20tL, bufY,
                                                      (short*)nullptr, (short*)nullptr, NN, 512, 256);
    colsum_T<<<64, 256, 0, stream>>>(bufY, Tflag, total, sumT);
    gcn2_combine<<<NN, 256, 0, stream>>>(bufY, Tflag, sumT, total);
    mfma_gemm<3, 0><<<dim3(128, 2), 256, 0, stream>>>(bufY, W21tH, W21tL, bufHs,
                                                      (short*)nullptr, (short*)nullptr, NN, 256, 256);
    colsum_T<<<64, 256, 0, stream>>>(bufHs, Tflag, tot2, sum2T);
    gcn2_combine<<<NN, 256, 0, stream>>>(bufHs, Tflag, sum2T, tot2);  // bufHs = H_

    // ---- bilinear head (3-pass split-f16); XB overlays dead bufY/Ybt ----
    mfma_gemm<3, 0><<<dim3(128, 4), 256, 0, stream>>>(x, bilwtH, bilwtL, XB,
                                                      (short*)nullptr, (short*)nullptr, NN, 512, 512);
    bilinear_kernel<<<ME / 4, 256, 0, stream>>>(XB, bufH, bufHs, src, dst, labels, bilb,
                                                out_logit, out_pred, lossp);
    loss_finalize<<<1, 256, 0, stream>>>(lossp, out);
}